// Round 1
// baseline (478.234 us; speedup 1.0000x reference)
//
#include <hip/hip_runtime.h>
#include <stdint.h>

#define NROWS 4096
#define NHID 1024
#define VSZ 50257
#define CC0 1675
#define CC1 5025
#define HEADSZ 1677
#define PD0 256
#define PD1 64
#define TSZ0 3350
#define TSZ1 45232

typedef __attribute__((ext_vector_type(8))) __bf16 bf16x8;
typedef __attribute__((ext_vector_type(4))) float f32x4;

__device__ __forceinline__ unsigned short f2bf(float f) {
  union { float f; uint32_t u; } v; v.f = f;
  return (unsigned short)((v.u + 0x7FFFu + ((v.u >> 16) & 1u)) >> 16);
}

__global__ void convert_f32_bf16(const float* __restrict__ src,
                                 unsigned short* __restrict__ dst, int n4) {
  int stride = gridDim.x * blockDim.x;
  for (int i = blockIdx.x * blockDim.x + threadIdx.x; i < n4; i += stride) {
    float4 v = reinterpret_cast<const float4*>(src)[i];
    ushort4 o;
    o.x = f2bf(v.x); o.y = f2bf(v.y); o.z = f2bf(v.z); o.w = f2bf(v.w);
    reinterpret_cast<ushort4*>(dst)[i] = o;
  }
}

__device__ __forceinline__ int tcol_of(int yv, int tmode) {
  if (tmode == 0) return yv < CC0 ? yv : (yv < CC1 ? CC0 : CC0 + 1);
  if (tmode == 1) { int r = yv - CC0; r = r < 0 ? 0 : r; return r > TSZ0 - 1 ? TSZ0 - 1 : r; }
  int r = yv - CC1; r = r < 0 ? 0 : r; return r > TSZ1 - 1 ? TSZ1 - 1 : r;
}

#define GLOAD(g, l) __builtin_amdgcn_global_load_lds( \
    (const __attribute__((address_space(1))) uint32_t*)(const void*)(g), \
    (__attribute__((address_space(3))) uint32_t*)(void*)(l), 16, 0, 0)

// C = A[4096,K] * B[N,K]^T, A/B bf16 (K-major both). Optional fused epilogue:
//   - Cout: store C as bf16 (ldc)
//   - sum_out: per-row atomicAdd of sum(exp(logit)) over this block's cols
//   - tgt_out: write logit at target col (from y + tmode)
__global__ void gemm_fused(const unsigned short* __restrict__ A, int lda,
                           const unsigned short* __restrict__ B, int ldb,
                           int N, int K,
                           const float* __restrict__ bias,
                           float* __restrict__ sum_out,
                           float* __restrict__ tgt_out,
                           const int* __restrict__ y, int tmode,
                           unsigned short* __restrict__ Cout, int ldc) {
  __shared__ unsigned short As[128 * 32];
  __shared__ unsigned short Bs[128 * 32];
  const int tid = threadIdx.x;
  const int lane = tid & 63;
  const int wid = tid >> 6;
  const int wrow = (wid >> 1) * 64;
  const int wcol = (wid & 1) * 64;
  const int brow = blockIdx.y * 128;
  const int bcol = blockIdx.x * 128;
  const int lr = lane & 15, lg = lane >> 4;

  f32x4 acc[4][4];
#pragma unroll
  for (int m = 0; m < 4; ++m)
#pragma unroll
    for (int n = 0; n < 4; ++n) acc[m][n] = (f32x4){0.f, 0.f, 0.f, 0.f};

  for (int k0 = 0; k0 < K; k0 += 32) {
#pragma unroll
    for (int c = 0; c < 2; ++c) {
      int g = wid * 128 + c * 64 + lane;       // 16B chunk id in [0,512)
      int row = g >> 2, ko = (g & 3) * 8;
      const unsigned short* ga = A + (size_t)(brow + row) * lda + k0 + ko;
      GLOAD(ga, &As[g * 8]);
      int bsrc = bcol + row; bsrc = bsrc < N ? bsrc : N - 1;   // clamp OOB cols
      const unsigned short* gb = B + (size_t)bsrc * ldb + k0 + ko;
      GLOAD(gb, &Bs[g * 8]);
    }
    __syncthreads();   // drains vmcnt -> LDS ready
    bf16x8 af[4], bfv[4];
#pragma unroll
    for (int m = 0; m < 4; ++m)
      af[m] = *(const bf16x8*)&As[(wrow + m * 16 + lr) * 32 + lg * 8];
#pragma unroll
    for (int n = 0; n < 4; ++n)
      bfv[n] = *(const bf16x8*)&Bs[(wcol + n * 16 + lr) * 32 + lg * 8];
#pragma unroll
    for (int m = 0; m < 4; ++m)
#pragma unroll
      for (int n = 0; n < 4; ++n)
        acc[m][n] = __builtin_amdgcn_mfma_f32_16x16x32_bf16(af[m], bfv[n], acc[m][n], 0, 0, 0);
    __syncthreads();
  }

  const int rowBase = brow + wrow;
  const int colBase = bcol + wcol;

  if (Cout) {
#pragma unroll
    for (int m = 0; m < 4; ++m)
#pragma unroll
      for (int n = 0; n < 4; ++n)
#pragma unroll
        for (int r = 0; r < 4; ++r) {
          int row = rowBase + m * 16 + lg * 4 + r;
          int col = colBase + n * 16 + lr;
          if (col < N) Cout[(size_t)row * ldc + col] = f2bf(acc[m][n][r]);
        }
  }
  if (sum_out) {
#pragma unroll
    for (int m = 0; m < 4; ++m) {
#pragma unroll
      for (int r = 0; r < 4; ++r) {
        int row = rowBase + m * 16 + lg * 4 + r;
        int t = tcol_of(y[row], tmode);
        float s = 0.f, tv = 0.f;
        int thit = 0;
#pragma unroll
        for (int n = 0; n < 4; ++n) {
          int col = colBase + n * 16 + lr;
          if (col < N) {
            float v = acc[m][n][r];
            if (bias) v += bias[col];
            s += __expf(v);
            if (col == t) { tv = v; thit = 1; }
          }
        }
        // reduce over the 16 lanes (lane&15) that share this row
        s += __shfl_xor(s, 1); s += __shfl_xor(s, 2);
        s += __shfl_xor(s, 4); s += __shfl_xor(s, 8);
        if (lr == 0) atomicAdd(&sum_out[row], s);
        if (thit) tgt_out[row] = tv;
      }
    }
  }
}

__global__ void finalize_kernel(const float* __restrict__ hs, const float* __restrict__ ht,
                                const float* __restrict__ s0, const float* __restrict__ t0,
                                const float* __restrict__ s1, const float* __restrict__ t1,
                                const int* __restrict__ y, float* __restrict__ out) {
  __shared__ float red[256];
  float local = 0.f;
  for (int n = threadIdx.x; n < NROWS; n += 256) {
    int yv = y[n];
    float o = ht[n] - logf(hs[n]);
    if (yv >= CC0) {
      if (yv < CC1) o += t0[n] - logf(s0[n]);
      else          o += t1[n] - logf(s1[n]);
    }
    out[n] = o;
    local += o;
  }
  red[threadIdx.x] = local;
  __syncthreads();
  for (int s = 128; s > 0; s >>= 1) {
    if ((int)threadIdx.x < s) red[threadIdx.x] += red[threadIdx.x + s];
    __syncthreads();
  }
  if (threadIdx.x == 0) out[NROWS] = -red[0] / (float)NROWS;
}

extern "C" void kernel_launch(void* const* d_in, const int* in_sizes, int n_in,
                              void* d_out, int out_size, void* d_ws, size_t ws_size,
                              hipStream_t stream) {
  const float* x      = (const float*)d_in[0];
  const int*   y      = (const int*)d_in[1];
  const float* head_w = (const float*)d_in[2];
  const float* head_b = (const float*)d_in[3];
  const float* proj0  = (const float*)d_in[4];
  const float* w0     = (const float*)d_in[5];
  const float* proj1  = (const float*)d_in[6];
  const float* w1     = (const float*)d_in[7];
  float* out = (float*)d_out;

  char* wp = (char*)d_ws;
  unsigned short* xb  = (unsigned short*)wp; wp += (size_t)NROWS * NHID * 2;
  unsigned short* hwb = (unsigned short*)wp; wp += (size_t)HEADSZ * NHID * 2;
  unsigned short* pb  = (unsigned short*)wp; wp += (size_t)(PD0 + PD1) * NHID * 2;
  unsigned short* w0b = (unsigned short*)wp; wp += (size_t)TSZ0 * PD0 * 2;
  unsigned short* w1b = (unsigned short*)wp; wp += (size_t)TSZ1 * PD1 * 2;
  unsigned short* hb  = (unsigned short*)wp; wp += (size_t)NROWS * (PD0 + PD1) * 2;
  float* hs = (float*)wp; wp += NROWS * 4;
  float* ht = (float*)wp; wp += NROWS * 4;
  float* s0 = (float*)wp; wp += NROWS * 4;
  float* t0 = (float*)wp; wp += NROWS * 4;
  float* s1 = (float*)wp; wp += NROWS * 4;
  float* t1 = (float*)wp; wp += NROWS * 4;

  hipMemsetAsync(hs, 0, 6 * NROWS * 4, stream);   // zero sum+tgt accumulators

  auto conv = [&](const float* s, unsigned short* d, int n) {
    int n4 = n / 4;
    int blocks = (n4 + 255) / 256; if (blocks > 2048) blocks = 2048;
    convert_f32_bf16<<<dim3(blocks), dim3(256), 0, stream>>>(s, d, n4);
  };
  conv(x,      xb,  NROWS * NHID);
  conv(head_w, hwb, HEADSZ * NHID);
  conv(proj0,  pb,             PD0 * NHID);
  conv(proj1,  pb + PD0 * NHID, PD1 * NHID);
  conv(w0,     w0b, TSZ0 * PD0);
  conv(w1,     w1b, TSZ1 * PD1);

  // h = x @ [proj0;proj1]^T  -> [4096, 320] bf16 (stored)
  gemm_fused<<<dim3((PD0 + PD1 + 127) / 128, NROWS / 128), 256, 0, stream>>>(
      xb, NHID, pb, NHID, PD0 + PD1, NHID,
      nullptr, nullptr, nullptr, nullptr, 0, hb, PD0 + PD1);
  // head logits: fused sumexp + target capture (bias = head_b)
  gemm_fused<<<dim3((HEADSZ + 127) / 128, NROWS / 128), 256, 0, stream>>>(
      xb, NHID, hwb, NHID, HEADSZ, NHID,
      head_b, hs, ht, y, 0, nullptr, 0);
  // cluster 0: h0 @ w0^T
  gemm_fused<<<dim3((TSZ0 + 127) / 128, NROWS / 128), 256, 0, stream>>>(
      hb, PD0 + PD1, w0b, PD0, TSZ0, PD0,
      nullptr, s0, t0, y, 1, nullptr, 0);
  // cluster 1: h1 @ w1^T
  gemm_fused<<<dim3((TSZ1 + 127) / 128, NROWS / 128), 256, 0, stream>>>(
      hb + PD0, PD0 + PD1, w1b, PD1, TSZ1, PD1,
      nullptr, s1, t1, y, 2, nullptr, 0);

  finalize_kernel<<<1, 256, 0, stream>>>(hs, ht, s0, t0, s1, t1, y, out);
}

// Round 2
// 475.329 us; speedup vs baseline: 1.0061x; 1.0061x over previous
//
#include <hip/hip_runtime.h>
#include <stdint.h>

#define NROWS 4096
#define NHID 1024
#define CC0 1675
#define CC1 5025
#define HEADSZ 1677
#define PD0 256
#define PD1 64
#define TSZ0 3350
#define TSZ1 45232
#define HPN (HEADSZ + PD0 + PD1)   // 1997: head + proj0 + proj1 fused B

typedef __attribute__((ext_vector_type(8))) __bf16 bf16x8;
typedef __attribute__((ext_vector_type(4))) float f32x4;

__device__ __forceinline__ unsigned short f2bf(float f) {
  union { float f; uint32_t u; } v; v.f = f;
  return (unsigned short)((v.u + 0x7FFFu + ((v.u >> 16) & 1u)) >> 16);
}

__global__ void convert_f32_bf16(const float* __restrict__ src,
                                 unsigned short* __restrict__ dst, int n4) {
  int stride = gridDim.x * blockDim.x;
  for (int i = blockIdx.x * blockDim.x + threadIdx.x; i < n4; i += stride) {
    float4 v = reinterpret_cast<const float4*>(src)[i];
    ushort4 o;
    o.x = f2bf(v.x); o.y = f2bf(v.y); o.z = f2bf(v.z); o.w = f2bf(v.w);
    reinterpret_cast<ushort4*>(dst)[i] = o;
  }
}

__device__ __forceinline__ int tcol_of(int yv, int tmode) {
  if (tmode == 0) return yv < CC0 ? yv : (yv < CC1 ? CC0 : CC0 + 1);
  if (tmode == 1) { int r = yv - CC0; r = r < 0 ? 0 : r; return r > TSZ0 - 1 ? TSZ0 - 1 : r; }
  int r = yv - CC1; r = r < 0 ? 0 : r; return r > TSZ1 - 1 ? TSZ1 - 1 : r;
}

#define GLOAD(g, l) __builtin_amdgcn_global_load_lds( \
    (const __attribute__((address_space(1))) uint32_t*)(const void*)(g), \
    (__attribute__((address_space(3))) uint32_t*)(void*)(l), 16, 0, 0)

// Involution swizzle on byte offsets within an 8KB [128][32]-bf16 tile:
// XOR bits 4-6 with bits 7-9 (row bits 1-3). Bank-verified: 2-way (free).
#define SWZB(L) ((L) ^ ((((L) >> 7) & 7) << 4))

// C = A[4096,K] * B[N,K]^T (bf16, K-major both). Block covers rows
// [by*128, by*128+128) and column tiles [bx*tpc, min((bx+1)*tpc, nTiles)).
// Epilogue per column tile, accumulated in registers:
//   col >= coutStart (if Cout): store bf16 to Cout[row][col-coutStart]
//   else: sacc += exp(v + bias), target-logit capture into tacc
// End of block: 16-lane shuffle reduce, one atomicAdd(sum_out[row]) per wave,
// owner-wave write of tgt_out[row].
__global__ void gemm_fused(const unsigned short* __restrict__ A, int lda,
                           const unsigned short* __restrict__ B, int ldb,
                           int N, int K, int tpc,
                           const float* __restrict__ bias,
                           float* __restrict__ sum_out,
                           float* __restrict__ tgt_out,
                           const int* __restrict__ y, int tmode,
                           unsigned short* __restrict__ Cout, int ldc,
                           int coutStart) {
  __shared__ unsigned short As[128 * 32];
  __shared__ unsigned short Bs[128 * 32];
  const int tid = threadIdx.x;
  const int lane = tid & 63;
  const int wid = tid >> 6;
  const int wrow = (wid >> 1) * 64;
  const int wcol = (wid & 1) * 64;
  const int brow = blockIdx.y * 128;
  const int lr = lane & 15, lg = lane >> 4;

  const int nTiles = (N + 127) >> 7;
  const int tile0 = blockIdx.x * tpc;
  int tile1 = tile0 + tpc; if (tile1 > nTiles) tile1 = nTiles;
  if (tile0 >= tile1) return;

  const int rowBase = brow + wrow;

  // Per-row state (16 rows per lane: m in 0..3, r in 0..3; row = m*16+lg*4+r)
  float sacc[4][4], tacc[4][4];
  int tcol[4][4];
#pragma unroll
  for (int m = 0; m < 4; ++m)
#pragma unroll
    for (int r = 0; r < 4; ++r) {
      sacc[m][r] = 0.f; tacc[m][r] = 0.f;
      tcol[m][r] = tcol_of(y[rowBase + m * 16 + lg * 4 + r], tmode);
    }

  for (int tile = tile0; tile < tile1; ++tile) {
    const int bcol = tile * 128;
    f32x4 acc[4][4];
#pragma unroll
    for (int m = 0; m < 4; ++m)
#pragma unroll
      for (int n = 0; n < 4; ++n) acc[m][n] = (f32x4){0.f, 0.f, 0.f, 0.f};

    for (int k0 = 0; k0 < K; k0 += 32) {
#pragma unroll
      for (int c = 0; c < 2; ++c) {
        int g = wid * 128 + c * 64 + lane;      // 16B chunk id in [0,512)
        int L = g * 16;                         // linear LDS dest byte
        int S = SWZB(L);                        // swizzled global source
        int row = S >> 6, ko = (S >> 4) & 3;
        const unsigned short* ga = A + (size_t)(brow + row) * lda + k0 + ko * 8;
        GLOAD(ga, (char*)As + L);
        int bsrc = bcol + row; bsrc = bsrc < N ? bsrc : N - 1;  // clamp OOB
        const unsigned short* gb = B + (size_t)bsrc * ldb + k0 + ko * 8;
        GLOAD(gb, (char*)Bs + L);
      }
      __syncthreads();   // drains vmcnt -> LDS ready
      bf16x8 af[4], bfv[4];
#pragma unroll
      for (int m = 0; m < 4; ++m) {
        int byteoff = SWZB((wrow + m * 16 + lr) * 64 + lg * 16);
        af[m] = *(const bf16x8*)((const char*)As + byteoff);
      }
#pragma unroll
      for (int n = 0; n < 4; ++n) {
        int byteoff = SWZB((wcol + n * 16 + lr) * 64 + lg * 16);
        bfv[n] = *(const bf16x8*)((const char*)Bs + byteoff);
      }
#pragma unroll
      for (int m = 0; m < 4; ++m)
#pragma unroll
        for (int n = 0; n < 4; ++n)
          acc[m][n] = __builtin_amdgcn_mfma_f32_16x16x32_bf16(af[m], bfv[n], acc[m][n], 0, 0, 0);
      __syncthreads();
    }

    // Register-only epilogue for this column tile.
#pragma unroll
    for (int m = 0; m < 4; ++m)
#pragma unroll
      for (int r = 0; r < 4; ++r) {
#pragma unroll
        for (int n = 0; n < 4; ++n) {
          int col = bcol + wcol + n * 16 + lr;
          if (col < N) {
            float v = acc[m][n][r];
            if (Cout && col >= coutStart) {
              int row = rowBase + m * 16 + lg * 4 + r;
              Cout[(size_t)row * ldc + (col - coutStart)] = f2bf(v);
            } else {
              if (bias) v += bias[col];
              sacc[m][r] += __expf(v);
              if (col == tcol[m][r]) tacc[m][r] += v;
            }
          }
        }
      }
  }

  // Final reduce across the 16 lanes sharing each row; one atomic per row.
#pragma unroll
  for (int m = 0; m < 4; ++m)
#pragma unroll
    for (int r = 0; r < 4; ++r) {
      float s = sacc[m][r], tv = tacc[m][r];
      s += __shfl_xor(s, 1); s += __shfl_xor(s, 2);
      s += __shfl_xor(s, 4); s += __shfl_xor(s, 8);
      tv += __shfl_xor(tv, 1); tv += __shfl_xor(tv, 2);
      tv += __shfl_xor(tv, 4); tv += __shfl_xor(tv, 8);
      int row = rowBase + m * 16 + lg * 4 + r;
      int t = tcol[m][r];
      if (lr == 0) {
        atomicAdd(&sum_out[row], s);
        // owner wave: t inside this block's tiles AND this wave's 64-col half
        if (t >= tile0 * 128 && t < tile1 * 128 && ((t >> 6) & 1) == (wid & 1))
          tgt_out[row] = tv;
      }
    }
}

__global__ void finalize_kernel(const float* __restrict__ hs, const float* __restrict__ ht,
                                const float* __restrict__ s0, const float* __restrict__ t0,
                                const float* __restrict__ s1, const float* __restrict__ t1,
                                const int* __restrict__ y, float* __restrict__ out) {
  __shared__ float red[256];
  float local = 0.f;
  for (int n = threadIdx.x; n < NROWS; n += 256) {
    int yv = y[n];
    float o = ht[n] - logf(hs[n]);
    if (yv >= CC0) {
      if (yv < CC1) o += t0[n] - logf(s0[n]);
      else          o += t1[n] - logf(s1[n]);
    }
    out[n] = o;
    local += o;
  }
  red[threadIdx.x] = local;
  __syncthreads();
  for (int s = 128; s > 0; s >>= 1) {
    if ((int)threadIdx.x < s) red[threadIdx.x] += red[threadIdx.x + s];
    __syncthreads();
  }
  if (threadIdx.x == 0) out[NROWS] = -red[0] / (float)NROWS;
}

extern "C" void kernel_launch(void* const* d_in, const int* in_sizes, int n_in,
                              void* d_out, int out_size, void* d_ws, size_t ws_size,
                              hipStream_t stream) {
  const float* x      = (const float*)d_in[0];
  const int*   y      = (const int*)d_in[1];
  const float* head_w = (const float*)d_in[2];
  const float* head_b = (const float*)d_in[3];
  const float* proj0  = (const float*)d_in[4];
  const float* w0     = (const float*)d_in[5];
  const float* proj1  = (const float*)d_in[6];
  const float* w1     = (const float*)d_in[7];
  float* out = (float*)d_out;

  char* wp = (char*)d_ws;
  unsigned short* xb  = (unsigned short*)wp; wp += (size_t)NROWS * NHID * 2;
  unsigned short* hpb = (unsigned short*)wp; wp += (size_t)HPN * NHID * 2;
  unsigned short* w0b = (unsigned short*)wp; wp += (size_t)TSZ0 * PD0 * 2;
  unsigned short* w1b = (unsigned short*)wp; wp += (size_t)TSZ1 * PD1 * 2;
  unsigned short* hb  = (unsigned short*)wp; wp += (size_t)NROWS * (PD0 + PD1) * 2;
  float* hs = (float*)wp; wp += NROWS * 4;
  float* ht = (float*)wp; wp += NROWS * 4;
  float* s0 = (float*)wp; wp += NROWS * 4;
  float* t0 = (float*)wp; wp += NROWS * 4;
  float* s1 = (float*)wp; wp += NROWS * 4;
  float* t1 = (float*)wp; wp += NROWS * 4;

  hipMemsetAsync(hs, 0, 6 * NROWS * 4, stream);   // zero sum/tgt accumulators

  auto conv = [&](const float* s, unsigned short* d, int n) {
    int n4 = n / 4;
    int blocks = (n4 + 255) / 256; if (blocks > 2048) blocks = 2048;
    convert_f32_bf16<<<dim3(blocks), dim3(256), 0, stream>>>(s, d, n4);
  };
  conv(x,      xb,  NROWS * NHID);
  conv(head_w, hpb, HEADSZ * NHID);
  conv(proj0,  hpb + (size_t)HEADSZ * NHID, PD0 * NHID);
  conv(proj1,  hpb + (size_t)(HEADSZ + PD0) * NHID, PD1 * NHID);
  conv(w0,     w0b, TSZ0 * PD0);
  conv(w1,     w1b, TSZ1 * PD1);

  // head + proj fused: logits cols [0,1677) -> exp-sum; cols [1677,1997) -> hb
  gemm_fused<<<dim3(16, 32), 256, 0, stream>>>(
      xb, NHID, hpb, NHID, HPN, NHID, 1,
      head_b, hs, ht, y, 0, hb, PD0 + PD1, HEADSZ);
  // cluster 0: hb[:, :256] @ w0^T  (N=3350, 27 tiles, 14 chunks x 2)
  gemm_fused<<<dim3(14, 32), 256, 0, stream>>>(
      hb, PD0 + PD1, w0b, PD0, TSZ0, PD0, 2,
      nullptr, s0, t0, y, 1, nullptr, 0, 0);
  // cluster 1: hb[:, 256:] @ w1^T  (N=45232, 354 tiles, 16 chunks x 23)
  gemm_fused<<<dim3(16, 32), 256, 0, stream>>>(
      hb + PD0, PD0 + PD1, w1b, PD1, TSZ1, PD1, 23,
      nullptr, s1, t1, y, 2, nullptr, 0, 0);

  finalize_kernel<<<1, 256, 0, stream>>>(hs, ht, s0, t0, s1, t1, y, out);
}

// Round 3
// 295.443 us; speedup vs baseline: 1.6187x; 1.6089x over previous
//
#include <hip/hip_runtime.h>
#include <stdint.h>

#define NROWS 4096
#define NHID 1024
#define CC0 1675
#define CC1 5025
#define HEADSZ 1677
#define PD0 256
#define PD1 64
#define TSZ0 3350
#define TSZ1 45232
#define HPN (HEADSZ + PD0 + PD1)   // 1997: head + proj0 + proj1 fused B

typedef __attribute__((ext_vector_type(8))) __bf16 bf16x8;
typedef __attribute__((ext_vector_type(4))) float f32x4;

__device__ __forceinline__ unsigned short f2bf(float f) {
  union { float f; uint32_t u; } v; v.f = f;
  return (unsigned short)((v.u + 0x7FFFu + ((v.u >> 16) & 1u)) >> 16);
}
__device__ __forceinline__ float bfl(uint32_t u) {  // low bf16 of a u32
  union { uint32_t u; float f; } v; v.u = u << 16; return v.f;
}
__device__ __forceinline__ float bfh(uint32_t u) {  // high bf16 of a u32
  union { uint32_t u; float f; } v; v.u = u & 0xFFFF0000u; return v.f;
}
__device__ __forceinline__ float bf1(unsigned short u) {
  union { uint32_t u; float f; } v; v.u = ((uint32_t)u) << 16; return v.f;
}

__global__ void convert_f32_bf16(const float* __restrict__ src,
                                 unsigned short* __restrict__ dst, int n4) {
  int stride = gridDim.x * blockDim.x;
  for (int i = blockIdx.x * blockDim.x + threadIdx.x; i < n4; i += stride) {
    float4 v = reinterpret_cast<const float4*>(src)[i];
    ushort4 o;
    o.x = f2bf(v.x); o.y = f2bf(v.y); o.z = f2bf(v.z); o.w = f2bf(v.w);
    reinterpret_cast<ushort4*>(dst)[i] = o;
  }
}

#define GLOAD(g, l) __builtin_amdgcn_global_load_lds( \
    (const __attribute__((address_space(1))) uint32_t*)(const void*)(g), \
    (__attribute__((address_space(3))) uint32_t*)(void*)(l), 16, 0, 0)

// Involution swizzle on byte offsets within an 8KB [128][32]-bf16 tile:
// XOR bits 4-6 with bits 7-9 (row bits 1-3). Bank-verified round 2: conflicts 0.
#define SWZB(L) ((L) ^ ((((L) >> 7) & 7) << 4))

// C = A[4096,K] * B[N,K]^T (bf16, K-major both). Block covers rows
// [by*128, +128) and column tiles [bx*tpc, min((bx+1)*tpc, nTiles)).
// Epilogue (registers only): col >= coutStart && Cout -> bf16 store;
// else sacc += exp(v + bias). End: 16-lane shuffle reduce, one
// atomicAdd(sum_out[row]) per wave.
__global__ __launch_bounds__(256, 2)
void gemm_fused(const unsigned short* __restrict__ A, int lda,
                const unsigned short* __restrict__ B, int ldb,
                int N, int K, int tpc,
                const float* __restrict__ bias,
                float* __restrict__ sum_out,
                unsigned short* __restrict__ Cout, int ldc,
                int coutStart) {
  __shared__ unsigned short As[128 * 32];
  __shared__ unsigned short Bs[128 * 32];
  const int tid = threadIdx.x;
  const int lane = tid & 63;
  const int wid = tid >> 6;
  const int wrow = (wid >> 1) * 64;
  const int wcol = (wid & 1) * 64;
  const int brow = blockIdx.y * 128;
  const int lr = lane & 15, lg = lane >> 4;

  const int nTiles = (N + 127) >> 7;
  const int tile0 = blockIdx.x * tpc;
  int tile1 = tile0 + tpc; if (tile1 > nTiles) tile1 = nTiles;
  if (tile0 >= tile1) return;

  const int rowBase = brow + wrow;

  float sacc[4][4];
#pragma unroll
  for (int m = 0; m < 4; ++m)
#pragma unroll
    for (int r = 0; r < 4; ++r) sacc[m][r] = 0.f;

  for (int tile = tile0; tile < tile1; ++tile) {
    const int bcol = tile * 128;
    f32x4 acc[4][4];
#pragma unroll
    for (int m = 0; m < 4; ++m)
#pragma unroll
      for (int n = 0; n < 4; ++n) acc[m][n] = (f32x4){0.f, 0.f, 0.f, 0.f};

    for (int k0 = 0; k0 < K; k0 += 32) {
#pragma unroll
      for (int c = 0; c < 2; ++c) {
        int g = wid * 128 + c * 64 + lane;      // 16B chunk id in [0,512)
        int L = g * 16;                         // linear LDS dest byte
        int S = SWZB(L);                        // swizzled global source
        int row = S >> 6, ko = (S >> 4) & 3;
        const unsigned short* ga = A + (size_t)(brow + row) * lda + k0 + ko * 8;
        GLOAD(ga, (char*)As + L);
        int bsrc = bcol + row; bsrc = bsrc < N ? bsrc : N - 1;  // clamp OOB
        const unsigned short* gb = B + (size_t)bsrc * ldb + k0 + ko * 8;
        GLOAD(gb, (char*)Bs + L);
      }
      __syncthreads();   // drains vmcnt -> LDS ready
      bf16x8 af[4], bfv[4];
#pragma unroll
      for (int m = 0; m < 4; ++m) {
        int byteoff = SWZB((wrow + m * 16 + lr) * 64 + lg * 16);
        af[m] = *(const bf16x8*)((const char*)As + byteoff);
      }
#pragma unroll
      for (int n = 0; n < 4; ++n) {
        int byteoff = SWZB((wcol + n * 16 + lr) * 64 + lg * 16);
        bfv[n] = *(const bf16x8*)((const char*)Bs + byteoff);
      }
#pragma unroll
      for (int m = 0; m < 4; ++m)
#pragma unroll
        for (int n = 0; n < 4; ++n)
          acc[m][n] = __builtin_amdgcn_mfma_f32_16x16x32_bf16(af[m], bfv[n], acc[m][n], 0, 0, 0);
      __syncthreads();
    }

    // Register-only epilogue for this column tile.
#pragma unroll
    for (int m = 0; m < 4; ++m)
#pragma unroll
      for (int r = 0; r < 4; ++r) {
#pragma unroll
        for (int n = 0; n < 4; ++n) {
          int col = bcol + wcol + n * 16 + lr;
          if (col < N) {
            float v = acc[m][n][r];
            if (Cout && col >= coutStart) {
              int row = rowBase + m * 16 + lg * 4 + r;
              Cout[(size_t)row * ldc + (col - coutStart)] = f2bf(v);
            } else {
              if (bias) v += bias[col];
              sacc[m][r] += __expf(v);
            }
          }
        }
      }
  }

  // Final reduce across the 16 lanes sharing each row; one atomic per row.
#pragma unroll
  for (int m = 0; m < 4; ++m)
#pragma unroll
    for (int r = 0; r < 4; ++r) {
      float s = sacc[m][r];
      s += __shfl_xor(s, 1); s += __shfl_xor(s, 2);
      s += __shfl_xor(s, 4); s += __shfl_xor(s, 8);
      if (lr == 0) atomicAdd(&sum_out[rowBase + m * 16 + lg * 4 + r], s);
    }
}

// One wave per row: target logits via direct dot products.
//   ht[row] = head logit at the row's head column (incl. bias)
//   tc[row] = cluster target logit (0 if target is in the head shortlist)
__global__ void target_logits(const unsigned short* __restrict__ xb,
                              const unsigned short* __restrict__ hwb,
                              const float* __restrict__ head_b,
                              const unsigned short* __restrict__ hb,
                              const unsigned short* __restrict__ w0b,
                              const unsigned short* __restrict__ w1b,
                              const int* __restrict__ y,
                              float* __restrict__ ht, float* __restrict__ tc) {
  int row = blockIdx.x * 4 + (threadIdx.x >> 6);
  int lane = threadIdx.x & 63;
  int yv = y[row];
  int th = yv < CC0 ? yv : (yv < CC1 ? CC0 : CC0 + 1);

  const unsigned short* xr = xb + (size_t)row * NHID + lane * 16;
  const unsigned short* wr = hwb + (size_t)th * NHID + lane * 16;
  uint4 xa = *(const uint4*)xr,       wa = *(const uint4*)wr;
  uint4 xc = *(const uint4*)(xr + 8), wc = *(const uint4*)(wr + 8);
  float s = 0.f;
  uint32_t xs[8] = {xa.x, xa.y, xa.z, xa.w, xc.x, xc.y, xc.z, xc.w};
  uint32_t ws[8] = {wa.x, wa.y, wa.z, wa.w, wc.x, wc.y, wc.z, wc.w};
#pragma unroll
  for (int j = 0; j < 8; ++j)
    s += bfl(xs[j]) * bfl(ws[j]) + bfh(xs[j]) * bfh(ws[j]);
#pragma unroll
  for (int d = 1; d < 64; d <<= 1) s += __shfl_xor(s, d);

  float cl = 0.f;
  if (yv >= CC0) {              // wave-uniform branch (row-uniform)
    if (yv < CC1) {
      int rel = yv - CC0;
      const unsigned short* hr = hb + (size_t)row * (PD0 + PD1) + lane * 4;
      const unsigned short* w0r = w0b + (size_t)rel * PD0 + lane * 4;
      uint2 ha = *(const uint2*)hr, wa0 = *(const uint2*)w0r;
      cl = bfl(ha.x) * bfl(wa0.x) + bfh(ha.x) * bfh(wa0.x)
         + bfl(ha.y) * bfl(wa0.y) + bfh(ha.y) * bfh(wa0.y);
    } else {
      int rel = yv - CC1;
      cl = bf1(hb[(size_t)row * (PD0 + PD1) + PD0 + lane])
         * bf1(w1b[(size_t)rel * PD1 + lane]);
    }
#pragma unroll
    for (int d = 1; d < 64; d <<= 1) cl += __shfl_xor(cl, d);
  }
  if (lane == 0) { ht[row] = s + head_b[th]; tc[row] = (yv < CC0) ? 0.f : cl; }
}

__global__ void finalize_kernel(const float* __restrict__ hs, const float* __restrict__ ht,
                                const float* __restrict__ s0, const float* __restrict__ s1,
                                const float* __restrict__ tc,
                                const int* __restrict__ y, float* __restrict__ out) {
  __shared__ float red[256];
  float local = 0.f;
  for (int n = threadIdx.x; n < NROWS; n += 256) {
    int yv = y[n];
    float o = ht[n] - logf(hs[n]);
    if (yv >= CC0) o += tc[n] - logf(yv < CC1 ? s0[n] : s1[n]);
    out[n] = o;
    local += o;
  }
  red[threadIdx.x] = local;
  __syncthreads();
  for (int s = 128; s > 0; s >>= 1) {
    if ((int)threadIdx.x < s) red[threadIdx.x] += red[threadIdx.x + s];
    __syncthreads();
  }
  if (threadIdx.x == 0) out[NROWS] = -red[0] / (float)NROWS;
}

extern "C" void kernel_launch(void* const* d_in, const int* in_sizes, int n_in,
                              void* d_out, int out_size, void* d_ws, size_t ws_size,
                              hipStream_t stream) {
  const float* x      = (const float*)d_in[0];
  const int*   y      = (const int*)d_in[1];
  const float* head_w = (const float*)d_in[2];
  const float* head_b = (const float*)d_in[3];
  const float* proj0  = (const float*)d_in[4];
  const float* w0     = (const float*)d_in[5];
  const float* proj1  = (const float*)d_in[6];
  const float* w1     = (const float*)d_in[7];
  float* out = (float*)d_out;

  char* wp = (char*)d_ws;
  unsigned short* xb  = (unsigned short*)wp; wp += (size_t)NROWS * NHID * 2;
  unsigned short* hpb = (unsigned short*)wp; wp += (size_t)HPN * NHID * 2;
  unsigned short* w0b = (unsigned short*)wp; wp += (size_t)TSZ0 * PD0 * 2;
  unsigned short* w1b = (unsigned short*)wp; wp += (size_t)TSZ1 * PD1 * 2;
  unsigned short* hb  = (unsigned short*)wp; wp += (size_t)NROWS * (PD0 + PD1) * 2;
  float* hs = (float*)wp; wp += NROWS * 4;
  float* s0 = (float*)wp; wp += NROWS * 4;
  float* s1 = (float*)wp; wp += NROWS * 4;
  float* ht = (float*)wp; wp += NROWS * 4;
  float* tc = (float*)wp; wp += NROWS * 4;

  hipMemsetAsync(hs, 0, 3 * NROWS * 4, stream);   // zero hs, s0, s1

  auto conv = [&](const float* s, unsigned short* d, int n) {
    int n4 = n / 4;
    int blocks = (n4 + 255) / 256; if (blocks > 2048) blocks = 2048;
    convert_f32_bf16<<<dim3(blocks), dim3(256), 0, stream>>>(s, d, n4);
  };
  conv(x,      xb,  NROWS * NHID);
  conv(head_w, hpb, HEADSZ * NHID);
  conv(proj0,  hpb + (size_t)HEADSZ * NHID, PD0 * NHID);
  conv(proj1,  hpb + (size_t)(HEADSZ + PD0) * NHID, PD1 * NHID);
  conv(w0,     w0b, TSZ0 * PD0);
  conv(w1,     w1b, TSZ1 * PD1);

  // head + proj fused: cols [0,1677) -> exp-sum; cols [1677,1997) -> hb store
  gemm_fused<<<dim3(16, 32), 256, 0, stream>>>(
      xb, NHID, hpb, NHID, HPN, NHID, 1,
      head_b, hs, hb, PD0 + PD1, HEADSZ);
  // target logits (needs hb) — one wave per row
  target_logits<<<dim3(NROWS / 4), 256, 0, stream>>>(
      xb, hpb, head_b, hb, w0b, w1b, y, ht, tc);
  // cluster 0: hb[:, :256] @ w0^T  (N=3350, 27 tiles, tpc=1)
  gemm_fused<<<dim3(27, 32), 256, 0, stream>>>(
      hb, PD0 + PD1, w0b, PD0, TSZ0, PD0, 1,
      nullptr, s0, nullptr, 0, 0);
  // cluster 1: hb[:, 256:] @ w1^T  (N=45232, 354 tiles, tpc=6, 59x32 blocks)
  gemm_fused<<<dim3(59, 32), 256, 0, stream>>>(
      hb + PD0, PD0 + PD1, w1b, PD1, TSZ1, PD1, 6,
      nullptr, s1, nullptr, 0, 0);

  finalize_kernel<<<1, 256, 0, stream>>>(hs, ht, s0, s1, tc, y, out);
}

// Round 4
// 205.497 us; speedup vs baseline: 2.3272x; 1.4377x over previous
//
#include <hip/hip_runtime.h>
#include <stdint.h>

#define NROWS 4096
#define NHID 1024
#define CC0 1675
#define CC1 5025
#define HEADSZ 1677
#define PD0 256
#define PD1 64
#define TSZ0 3350
#define TSZ1 45232
#define HPN (HEADSZ + PD0 + PD1)   // 1997: head + proj0 + proj1 fused B

typedef __attribute__((ext_vector_type(8))) __bf16 bf16x8;
typedef __attribute__((ext_vector_type(4))) float f32x4;

__device__ __forceinline__ unsigned short f2bf(float f) {
  union { float f; uint32_t u; } v; v.f = f;
  return (unsigned short)((v.u + 0x7FFFu + ((v.u >> 16) & 1u)) >> 16);
}
__device__ __forceinline__ float bfl(uint32_t u) {
  union { uint32_t u; float f; } v; v.u = u << 16; return v.f;
}
__device__ __forceinline__ float bfh(uint32_t u) {
  union { uint32_t u; float f; } v; v.u = u & 0xFFFF0000u; return v.f;
}
__device__ __forceinline__ float bf1(unsigned short u) {
  union { uint32_t u; float f; } v; v.u = ((uint32_t)u) << 16; return v.f;
}

__global__ void convert_f32_bf16(const float* __restrict__ src,
                                 unsigned short* __restrict__ dst, int n4) {
  int stride = gridDim.x * blockDim.x;
  for (int i = blockIdx.x * blockDim.x + threadIdx.x; i < n4; i += stride) {
    float4 v = reinterpret_cast<const float4*>(src)[i];
    ushort4 o;
    o.x = f2bf(v.x); o.y = f2bf(v.y); o.z = f2bf(v.z); o.w = f2bf(v.w);
    reinterpret_cast<ushort4*>(dst)[i] = o;
  }
}

#define GLOAD(g, l) __builtin_amdgcn_global_load_lds( \
    (const __attribute__((address_space(1))) uint32_t*)(const void*)(g), \
    (__attribute__((address_space(3))) uint32_t*)(void*)(l), 16, 0, 0)

// Involution swizzle on byte offsets within an 8KB [128][32]-bf16 tile:
// XOR bits 4-6 with bits 7-9. Bank-verified (round 2): conflicts 0.
#define SWZB(L) ((L) ^ ((((L) >> 7) & 7) << 4))

// C = A[4096,K] * B[N,K]^T (bf16, K-major both). 1D grid, XCD-swizzled:
// consecutive sids share the column chunk => B-tiles stay L2-local per XCD.
// 2-phase pipeline: prefetch step s+1 into buf^1 while computing buf.
// Epilogue per tile (registers only): col >= coutStart && Cout -> bf16 store;
// else sacc += exp(v+bias). End: 16-lane shuffle reduce, 1 atomic per row.
__global__ __launch_bounds__(256, 2)
void gemm_fused(const unsigned short* __restrict__ A, int lda,
                const unsigned short* __restrict__ B, int ldb,
                int N, int K, int tpc,
                const float* __restrict__ bias,
                float* __restrict__ sum_out,
                unsigned short* __restrict__ Cout, int ldc,
                int coutStart) {
  __shared__ __align__(16) unsigned short As[2][128 * 32];
  __shared__ __align__(16) unsigned short Bs[2][128 * 32];
  const int tid = threadIdx.x;
  const int lane = tid & 63;
  const int wid = tid >> 6;
  const int wrow = (wid >> 1) * 64;
  const int wcol = (wid & 1) * 64;
  const int lr = lane & 15, lg = lane >> 4;

  // bijective XCD swizzle (gridDim.x % 8 == 0 by construction)
  const int cpx = gridDim.x >> 3;
  const int sid = ((int)blockIdx.x & 7) * cpx + ((int)blockIdx.x >> 3);
  const int rowBlk = sid & 31;            // 32 row blocks of 128
  const int colChunk = sid >> 5;
  const int brow = rowBlk * 128;
  const int nTiles = (N + 127) >> 7;
  const int tile0 = colChunk * tpc;
  const int tile1 = min(tile0 + tpc, nTiles);
  const int nsteps = (tile1 - tile0) * (K >> 5);
  const int rowBase = brow + wrow;

  float sacc[4][4];
#pragma unroll
  for (int m = 0; m < 4; ++m)
#pragma unroll
    for (int r = 0; r < 4; ++r) sacc[m][r] = 0.f;

  auto stage = [&](int b, int tt, int kk) {
#pragma unroll
    for (int c = 0; c < 2; ++c) {
      int g = wid * 128 + c * 64 + lane;    // 16B chunk id in [0,512)
      int L = g * 16;                       // linear LDS dest byte
      int S = SWZB(L);                      // pre-swizzled global source
      int row = S >> 6, ko = (S >> 4) & 3;
      GLOAD(A + (size_t)(brow + row) * lda + kk + ko * 8, (char*)As[b] + L);
      int bsrc = tt * 128 + row; bsrc = bsrc < N ? bsrc : N - 1;
      GLOAD(B + (size_t)bsrc * ldb + kk + ko * 8, (char*)Bs[b] + L);
    }
  };

  f32x4 acc[4][4];
#pragma unroll
  for (int m = 0; m < 4; ++m)
#pragma unroll
    for (int n = 0; n < 4; ++n) acc[m][n] = (f32x4){0.f, 0.f, 0.f, 0.f};

  stage(0, tile0, 0);
  asm volatile("s_waitcnt vmcnt(0)" ::: "memory");
  __builtin_amdgcn_s_barrier();

  int tile = tile0, k0 = 0;
  for (int s = 0; s < nsteps; ++s) {
    const int cur = s & 1;
    int k0n = k0 + 32, tn = tile;
    if (k0n == K) { k0n = 0; tn = tile + 1; }
    if (s + 1 < nsteps) stage(cur ^ 1, tn, k0n);   // prefetch (in flight)

    bf16x8 af[4], bfv[4];
#pragma unroll
    for (int m = 0; m < 4; ++m)
      af[m] = *(const bf16x8*)((const char*)As[cur] +
                               SWZB((wrow + m * 16 + lr) * 64 + lg * 16));
#pragma unroll
    for (int n = 0; n < 4; ++n)
      bfv[n] = *(const bf16x8*)((const char*)Bs[cur] +
                                SWZB((wcol + n * 16 + lr) * 64 + lg * 16));
#pragma unroll
    for (int m = 0; m < 4; ++m)
#pragma unroll
      for (int n = 0; n < 4; ++n)
        acc[m][n] = __builtin_amdgcn_mfma_f32_16x16x32_bf16(af[m], bfv[n], acc[m][n], 0, 0, 0);

    if (tn != tile) {                      // tile finished: fused epilogue
      const int cb = tile * 128 + wcol;
#pragma unroll
      for (int m = 0; m < 4; ++m)
#pragma unroll
        for (int n = 0; n < 4; ++n) {
#pragma unroll
          for (int r = 0; r < 4; ++r) {
            int col = cb + n * 16 + lr;
            if (col < N) {
              float v = acc[m][n][r];
              if (Cout && col >= coutStart) {
                int row = rowBase + m * 16 + lg * 4 + r;
                Cout[(size_t)row * ldc + (col - coutStart)] = f2bf(v);
              } else {
                if (bias) v += bias[col];
                sacc[m][r] += __expf(v);
              }
            }
          }
          acc[m][n] = (f32x4){0.f, 0.f, 0.f, 0.f};
        }
    }

    asm volatile("s_waitcnt vmcnt(0)" ::: "memory");  // prefetch landed
    __builtin_amdgcn_s_barrier();                     // buf swap safe
    tile = tn; k0 = k0n;
  }

  // Final reduce across the 16 lanes sharing each row; one atomic per row.
#pragma unroll
  for (int m = 0; m < 4; ++m)
#pragma unroll
    for (int r = 0; r < 4; ++r) {
      float s = sacc[m][r];
      s += __shfl_xor(s, 1); s += __shfl_xor(s, 2);
      s += __shfl_xor(s, 4); s += __shfl_xor(s, 8);
      if (lr == 0) atomicAdd(&sum_out[rowBase + m * 16 + lg * 4 + r], s);
    }
}

// One wave per row: target logits via direct dot products.
__global__ void target_logits(const unsigned short* __restrict__ xb,
                              const unsigned short* __restrict__ hwb,
                              const float* __restrict__ head_b,
                              const unsigned short* __restrict__ hb,
                              const unsigned short* __restrict__ w0b,
                              const unsigned short* __restrict__ w1b,
                              const int* __restrict__ y,
                              float* __restrict__ ht, float* __restrict__ tc) {
  int row = blockIdx.x * 4 + (threadIdx.x >> 6);
  int lane = threadIdx.x & 63;
  int yv = y[row];
  int th = yv < CC0 ? yv : (yv < CC1 ? CC0 : CC0 + 1);

  const unsigned short* xr = xb + (size_t)row * NHID + lane * 16;
  const unsigned short* wr = hwb + (size_t)th * NHID + lane * 16;
  uint4 xa = *(const uint4*)xr,       wa = *(const uint4*)wr;
  uint4 xc = *(const uint4*)(xr + 8), wc = *(const uint4*)(wr + 8);
  float s = 0.f;
  uint32_t xs[8] = {xa.x, xa.y, xa.z, xa.w, xc.x, xc.y, xc.z, xc.w};
  uint32_t ws[8] = {wa.x, wa.y, wa.z, wa.w, wc.x, wc.y, wc.z, wc.w};
#pragma unroll
  for (int j = 0; j < 8; ++j)
    s += bfl(xs[j]) * bfl(ws[j]) + bfh(xs[j]) * bfh(ws[j]);
#pragma unroll
  for (int d = 1; d < 64; d <<= 1) s += __shfl_xor(s, d);

  float cl = 0.f;
  if (yv >= CC0) {              // wave-uniform branch (row-uniform)
    if (yv < CC1) {
      int rel = yv - CC0;
      const unsigned short* hr = hb + (size_t)row * (PD0 + PD1) + lane * 4;
      const unsigned short* w0r = w0b + (size_t)rel * PD0 + lane * 4;
      uint2 ha = *(const uint2*)hr, wa0 = *(const uint2*)w0r;
      cl = bfl(ha.x) * bfl(wa0.x) + bfh(ha.x) * bfh(wa0.x)
         + bfl(ha.y) * bfl(wa0.y) + bfh(ha.y) * bfh(wa0.y);
    } else {
      int rel = yv - CC1;
      cl = bf1(hb[(size_t)row * (PD0 + PD1) + PD0 + lane])
         * bf1(w1b[(size_t)rel * PD1 + lane]);
    }
#pragma unroll
    for (int d = 1; d < 64; d <<= 1) cl += __shfl_xor(cl, d);
  }
  if (lane == 0) { ht[row] = s + head_b[th]; tc[row] = (yv < CC0) ? 0.f : cl; }
}

__global__ void finalize_kernel(const float* __restrict__ hs, const float* __restrict__ ht,
                                const float* __restrict__ s0, const float* __restrict__ s1,
                                const float* __restrict__ tc,
                                const int* __restrict__ y, float* __restrict__ out) {
  __shared__ float red[256];
  float local = 0.f;
  for (int n = threadIdx.x; n < NROWS; n += 256) {
    int yv = y[n];
    float o = ht[n] - logf(hs[n]);
    if (yv >= CC0) o += tc[n] - logf(yv < CC1 ? s0[n] : s1[n]);
    out[n] = o;
    local += o;
  }
  red[threadIdx.x] = local;
  __syncthreads();
  for (int s = 128; s > 0; s >>= 1) {
    if ((int)threadIdx.x < s) red[threadIdx.x] += red[threadIdx.x + s];
    __syncthreads();
  }
  if (threadIdx.x == 0) out[NROWS] = -red[0] / (float)NROWS;
}

extern "C" void kernel_launch(void* const* d_in, const int* in_sizes, int n_in,
                              void* d_out, int out_size, void* d_ws, size_t ws_size,
                              hipStream_t stream) {
  const float* x      = (const float*)d_in[0];
  const int*   y      = (const int*)d_in[1];
  const float* head_w = (const float*)d_in[2];
  const float* head_b = (const float*)d_in[3];
  const float* proj0  = (const float*)d_in[4];
  const float* w0     = (const float*)d_in[5];
  const float* proj1  = (const float*)d_in[6];
  const float* w1     = (const float*)d_in[7];
  float* out = (float*)d_out;

  char* wp = (char*)d_ws;
  unsigned short* xb  = (unsigned short*)wp; wp += (size_t)NROWS * NHID * 2;
  unsigned short* hpb = (unsigned short*)wp; wp += (size_t)HPN * NHID * 2;
  unsigned short* w0b = (unsigned short*)wp; wp += (size_t)TSZ0 * PD0 * 2;
  unsigned short* w1b = (unsigned short*)wp; wp += (size_t)TSZ1 * PD1 * 2;
  unsigned short* hb  = (unsigned short*)wp; wp += (size_t)NROWS * (PD0 + PD1) * 2;
  float* hs = (float*)wp; wp += NROWS * 4;
  float* s0 = (float*)wp; wp += NROWS * 4;
  float* s1 = (float*)wp; wp += NROWS * 4;
  float* ht = (float*)wp; wp += NROWS * 4;
  float* tc = (float*)wp; wp += NROWS * 4;

  hipMemsetAsync(hs, 0, 3 * NROWS * 4, stream);   // zero hs, s0, s1

  auto conv = [&](const float* s, unsigned short* d, int n) {
    int n4 = n / 4;
    int blocks = (n4 + 255) / 256; if (blocks > 2048) blocks = 2048;
    convert_f32_bf16<<<dim3(blocks), dim3(256), 0, stream>>>(s, d, n4);
  };
  conv(x,      xb,  NROWS * NHID);
  conv(head_w, hpb, HEADSZ * NHID);
  conv(proj0,  hpb + (size_t)HEADSZ * NHID, PD0 * NHID);
  conv(proj1,  hpb + (size_t)(HEADSZ + PD0) * NHID, PD1 * NHID);
  conv(w0,     w0b, TSZ0 * PD0);
  conv(w1,     w1b, TSZ1 * PD1);

  // head + proj fused: cols [0,1677) -> exp-sum; cols [1677,1997) -> hb store
  // nTiles=16, tpc=1 -> 16 chunks x 32 rowBlks = 512 blocks
  gemm_fused<<<dim3(512), 256, 0, stream>>>(
      xb, NHID, hpb, NHID, HPN, NHID, 1,
      head_b, hs, hb, PD0 + PD1, HEADSZ);
  // target logits (needs hb) — one wave per row
  target_logits<<<dim3(NROWS / 4), 256, 0, stream>>>(
      xb, hpb, head_b, hb, w0b, w1b, y, ht, tc);
  // cluster 0: nTiles=27, tpc=3 -> 9 chunks x 32 = 288 blocks, 24 steps
  gemm_fused<<<dim3(288), 256, 0, stream>>>(
      hb, PD0 + PD1, w0b, PD0, TSZ0, PD0, 3,
      nullptr, s0, nullptr, 0, 0);
  // cluster 1: nTiles=354, tpc=6 -> 59 chunks x 32 = 1888 blocks, 12 steps
  gemm_fused<<<dim3(1888), 256, 0, stream>>>(
      hb + PD0, PD0 + PD1, w1b, PD1, TSZ1, PD1, 6,
      nullptr, s1, nullptr, 0, 0);

  finalize_kernel<<<1, 256, 0, stream>>>(hs, ht, s0, s1, tc, y, out);
}

// Round 5
// 167.915 us; speedup vs baseline: 2.8481x; 1.2238x over previous
//
#include <hip/hip_runtime.h>
#include <stdint.h>

#define NROWS 4096
#define NHID 1024
#define CC0 1675
#define CC1 5025
#define HEADSZ 1677
#define PD0 256
#define PD1 64
#define TSZ0 3350
#define TSZ1 45232
#define HPN (HEADSZ + PD0 + PD1)   // 1997: head + proj0 + proj1 fused B
#define NT1 354                    // c1 column tiles (59 chunks x 6)
#define TPC1 6

typedef __attribute__((ext_vector_type(8))) __bf16 bf16x8;
typedef __attribute__((ext_vector_type(4))) float f32x4;

__device__ __forceinline__ unsigned short f2bf(float f) {
  union { float f; uint32_t u; } v; v.f = f;
  return (unsigned short)((v.u + 0x7FFFu + ((v.u >> 16) & 1u)) >> 16);
}
__device__ __forceinline__ float bfl(uint32_t u) {
  union { uint32_t u; float f; } v; v.u = u << 16; return v.f;
}
__device__ __forceinline__ float bfh(uint32_t u) {
  union { uint32_t u; float f; } v; v.u = u & 0xFFFF0000u; return v.f;
}
__device__ __forceinline__ float bf1(unsigned short u) {
  union { uint32_t u; float f; } v; v.u = ((uint32_t)u) << 16; return v.f;
}

__global__ void convert_f32_bf16(const float* __restrict__ src,
                                 unsigned short* __restrict__ dst, int n4) {
  int stride = gridDim.x * blockDim.x;
  for (int i = blockIdx.x * blockDim.x + threadIdx.x; i < n4; i += stride) {
    float4 v = reinterpret_cast<const float4*>(src)[i];
    ushort4 o;
    o.x = f2bf(v.x); o.y = f2bf(v.y); o.z = f2bf(v.z); o.w = f2bf(v.w);
    reinterpret_cast<ushort4*>(dst)[i] = o;
  }
}

#define GLOAD(g, l) __builtin_amdgcn_global_load_lds( \
    (const __attribute__((address_space(1))) uint32_t*)(const void*)(g), \
    (__attribute__((address_space(3))) uint32_t*)(void*)(l), 16, 0, 0)

// Involution swizzle on byte offsets within an 8KB [128][32]-bf16 tile:
// XOR bits 4-6 with bits 7-9. Bank-verified (round 2): conflicts 0.
#define SWZB(L) ((L) ^ ((((L) >> 7) & 7) << 4))

// ---------------- LDS-pipeline GEMM (head+proj, cluster 0) ----------------
__global__ __launch_bounds__(256, 2)
void gemm_fused(const unsigned short* __restrict__ A, int lda,
                const unsigned short* __restrict__ B, int ldb,
                int N, int K, int tpc,
                const float* __restrict__ bias,
                float* __restrict__ sum_out,
                unsigned short* __restrict__ Cout, int ldc,
                int coutStart) {
  __shared__ __align__(16) unsigned short As[2][128 * 32];
  __shared__ __align__(16) unsigned short Bs[2][128 * 32];
  const int tid = threadIdx.x;
  const int lane = tid & 63;
  const int wid = tid >> 6;
  const int wrow = (wid >> 1) * 64;
  const int wcol = (wid & 1) * 64;
  const int lr = lane & 15, lg = lane >> 4;

  const int cpx = gridDim.x >> 3;
  const int sid = ((int)blockIdx.x & 7) * cpx + ((int)blockIdx.x >> 3);
  const int rowBlk = sid & 31;
  const int colChunk = sid >> 5;
  const int brow = rowBlk * 128;
  const int nTiles = (N + 127) >> 7;
  const int tile0 = colChunk * tpc;
  const int tile1 = min(tile0 + tpc, nTiles);
  const int nsteps = (tile1 - tile0) * (K >> 5);
  const int rowBase = brow + wrow;

  float sacc[4][4];
#pragma unroll
  for (int m = 0; m < 4; ++m)
#pragma unroll
    for (int r = 0; r < 4; ++r) sacc[m][r] = 0.f;

  auto stage = [&](int b, int tt, int kk) {
#pragma unroll
    for (int c = 0; c < 2; ++c) {
      int g = wid * 128 + c * 64 + lane;
      int L = g * 16;
      int S = SWZB(L);
      int row = S >> 6, ko = (S >> 4) & 3;
      GLOAD(A + (size_t)(brow + row) * lda + kk + ko * 8, (char*)As[b] + L);
      int bsrc = tt * 128 + row; bsrc = bsrc < N ? bsrc : N - 1;
      GLOAD(B + (size_t)bsrc * ldb + kk + ko * 8, (char*)Bs[b] + L);
    }
  };

  f32x4 acc[4][4];
#pragma unroll
  for (int m = 0; m < 4; ++m)
#pragma unroll
    for (int n = 0; n < 4; ++n) acc[m][n] = (f32x4){0.f, 0.f, 0.f, 0.f};

  stage(0, tile0, 0);
  asm volatile("s_waitcnt vmcnt(0)" ::: "memory");
  __builtin_amdgcn_s_barrier();

  int tile = tile0, k0 = 0;
  for (int s = 0; s < nsteps; ++s) {
    const int cur = s & 1;
    int k0n = k0 + 32, tn = tile;
    if (k0n == K) { k0n = 0; tn = tile + 1; }
    if (s + 1 < nsteps) stage(cur ^ 1, tn, k0n);

    bf16x8 af[4], bfv[4];
#pragma unroll
    for (int m = 0; m < 4; ++m)
      af[m] = *(const bf16x8*)((const char*)As[cur] +
                               SWZB((wrow + m * 16 + lr) * 64 + lg * 16));
#pragma unroll
    for (int n = 0; n < 4; ++n)
      bfv[n] = *(const bf16x8*)((const char*)Bs[cur] +
                                SWZB((wcol + n * 16 + lr) * 64 + lg * 16));
#pragma unroll
    for (int m = 0; m < 4; ++m)
#pragma unroll
      for (int n = 0; n < 4; ++n)
        acc[m][n] = __builtin_amdgcn_mfma_f32_16x16x32_bf16(af[m], bfv[n], acc[m][n], 0, 0, 0);

    if (tn != tile) {
      const int cb = tile * 128 + wcol;
#pragma unroll
      for (int m = 0; m < 4; ++m)
#pragma unroll
        for (int n = 0; n < 4; ++n) {
#pragma unroll
          for (int r = 0; r < 4; ++r) {
            int col = cb + n * 16 + lr;
            if (col < N) {
              float v = acc[m][n][r];
              if (Cout && col >= coutStart) {
                int row = rowBase + m * 16 + lg * 4 + r;
                Cout[(size_t)row * ldc + (col - coutStart)] = f2bf(v);
              } else {
                if (bias) v += bias[col];
                sacc[m][r] += __expf(v);
              }
            }
          }
          acc[m][n] = (f32x4){0.f, 0.f, 0.f, 0.f};
        }
    }

    asm volatile("s_waitcnt vmcnt(0)" ::: "memory");
    __builtin_amdgcn_s_barrier();
    tile = tn; k0 = k0n;
  }

#pragma unroll
  for (int m = 0; m < 4; ++m)
#pragma unroll
    for (int r = 0; r < 4; ++r) {
      float s = sacc[m][r];
      s += __shfl_xor(s, 1); s += __shfl_xor(s, 2);
      s += __shfl_xor(s, 4); s += __shfl_xor(s, 8);
      if (lr == 0) atomicAdd(&sum_out[rowBase + m * 16 + lg * 4 + r], s);
    }
}

// ---------------- register-direct streaming GEMM (cluster 1) ----------------
// A = hb+PD0 [4096 x 64] (lda=320), B = w1b [45232 x 64]. K=64 fits A and B
// fragments entirely in registers: no LDS, no barriers, waves independent.
// Per tile: 8 global_load_dwordx4 (B frags), 32 MFMA, 64-exp epilogue.
// Named double buffers b0/b1 (rule: no runtime-indexed reg arrays).
#define LOADB1(t, b) do {                                               \
    int cb_ = (t) * 128 + wcol;                                         \
    _Pragma("unroll")                                                   \
    for (int n_ = 0; n_ < 4; ++n_) {                                    \
      int col_ = cb_ + n_ * 16 + lr;                                    \
      col_ = col_ < TSZ1 ? col_ : TSZ1 - 1;                             \
      const unsigned short* p_ = B + (size_t)col_ * PD1 + lg * 8;       \
      b[n_][0] = *(const bf16x8*)p_;                                    \
      b[n_][1] = *(const bf16x8*)(p_ + 32);                             \
    } } while (0)

#define COMPUTE1(t, b) do {                                             \
    f32x4 acc_[4][4];                                                   \
    _Pragma("unroll")                                                   \
    for (int m_ = 0; m_ < 4; ++m_)                                      \
      _Pragma("unroll")                                                 \
      for (int n_ = 0; n_ < 4; ++n_) {                                  \
        f32x4 a_ = (f32x4){0.f, 0.f, 0.f, 0.f};                         \
        a_ = __builtin_amdgcn_mfma_f32_16x16x32_bf16(af[m_][0], b[n_][0], a_, 0, 0, 0); \
        a_ = __builtin_amdgcn_mfma_f32_16x16x32_bf16(af[m_][1], b[n_][1], a_, 0, 0, 0); \
        acc_[m_][n_] = a_;                                              \
      }                                                                 \
    int cb_ = (t) * 128 + wcol;                                         \
    if (cb_ + 63 < TSZ1) {                                              \
      _Pragma("unroll")                                                 \
      for (int m_ = 0; m_ < 4; ++m_)                                    \
        _Pragma("unroll")                                               \
        for (int r_ = 0; r_ < 4; ++r_) {                                \
          float s_ = __expf(acc_[m_][0][r_]) + __expf(acc_[m_][1][r_])  \
                   + __expf(acc_[m_][2][r_]) + __expf(acc_[m_][3][r_]); \
          sacc[m_][r_] += s_;                                           \
        }                                                               \
    } else {                                                            \
      _Pragma("unroll")                                                 \
      for (int m_ = 0; m_ < 4; ++m_)                                    \
        _Pragma("unroll")                                               \
        for (int r_ = 0; r_ < 4; ++r_) {                                \
          float s_ = 0.f;                                               \
          _Pragma("unroll")                                             \
          for (int n_ = 0; n_ < 4; ++n_)                                \
            if (cb_ + n_ * 16 + lr < TSZ1) s_ += __expf(acc_[m_][n_][r_]); \
          sacc[m_][r_] += s_;                                           \
        }                                                               \
    } } while (0)

__global__ __launch_bounds__(256, 2)
void gemm_c1_reg(const unsigned short* __restrict__ A,
                 const unsigned short* __restrict__ B,
                 float* __restrict__ sum_out) {
  const int lane = threadIdx.x & 63;
  const int wid = threadIdx.x >> 6;
  const int lr = lane & 15, lg = lane >> 4;

  const int cpx = gridDim.x >> 3;
  const int sid = ((int)blockIdx.x & 7) * cpx + ((int)blockIdx.x >> 3);
  const int rowBlk = sid & 31;
  const int colChunk = sid >> 5;
  const int rowBase = rowBlk * 128 + (wid >> 1) * 64;   // wave's 64-row base
  const int wcol = (wid & 1) * 64;
  const int tile0 = colChunk * TPC1;                    // 6 tiles, exact

  // A fragments: loaded once (tile-invariant). 32 VGPRs.
  bf16x8 af[4][2];
#pragma unroll
  for (int m = 0; m < 4; ++m) {
    const unsigned short* p = A + (size_t)(rowBase + m * 16 + lr) * (PD0 + PD1) + lg * 8;
    af[m][0] = *(const bf16x8*)p;
    af[m][1] = *(const bf16x8*)(p + 32);
  }

  float sacc[4][4];
#pragma unroll
  for (int m = 0; m < 4; ++m)
#pragma unroll
    for (int r = 0; r < 4; ++r) sacc[m][r] = 0.f;

  bf16x8 b0[4][2], b1[4][2];
  LOADB1(tile0, b0);
#pragma unroll 1
  for (int t = tile0; t < tile0 + TPC1; t += 2) {
    LOADB1(t + 1, b1);          // in flight over COMPUTE(t)
    COMPUTE1(t, b0);
    if (t + 2 < tile0 + TPC1) LOADB1(t + 2, b0);
    COMPUTE1(t + 1, b1);
  }

#pragma unroll
  for (int m = 0; m < 4; ++m)
#pragma unroll
    for (int r = 0; r < 4; ++r) {
      float s = sacc[m][r];
      s += __shfl_xor(s, 1); s += __shfl_xor(s, 2);
      s += __shfl_xor(s, 4); s += __shfl_xor(s, 8);
      if (lr == 0) atomicAdd(&sum_out[rowBase + m * 16 + lg * 4 + r], s);
    }
}

// One wave per row: target logits via direct dot products.
__global__ void target_logits(const unsigned short* __restrict__ xb,
                              const unsigned short* __restrict__ hwb,
                              const float* __restrict__ head_b,
                              const unsigned short* __restrict__ hb,
                              const unsigned short* __restrict__ w0b,
                              const unsigned short* __restrict__ w1b,
                              const int* __restrict__ y,
                              float* __restrict__ ht, float* __restrict__ tc) {
  int row = blockIdx.x * 4 + (threadIdx.x >> 6);
  int lane = threadIdx.x & 63;
  int yv = y[row];
  int th = yv < CC0 ? yv : (yv < CC1 ? CC0 : CC0 + 1);

  const unsigned short* xr = xb + (size_t)row * NHID + lane * 16;
  const unsigned short* wr = hwb + (size_t)th * NHID + lane * 16;
  uint4 xa = *(const uint4*)xr,       wa = *(const uint4*)wr;
  uint4 xc = *(const uint4*)(xr + 8), wc = *(const uint4*)(wr + 8);
  float s = 0.f;
  uint32_t xs[8] = {xa.x, xa.y, xa.z, xa.w, xc.x, xc.y, xc.z, xc.w};
  uint32_t ws[8] = {wa.x, wa.y, wa.z, wa.w, wc.x, wc.y, wc.z, wc.w};
#pragma unroll
  for (int j = 0; j < 8; ++j)
    s += bfl(xs[j]) * bfl(ws[j]) + bfh(xs[j]) * bfh(ws[j]);
#pragma unroll
  for (int d = 1; d < 64; d <<= 1) s += __shfl_xor(s, d);

  float cl = 0.f;
  if (yv >= CC0) {
    if (yv < CC1) {
      int rel = yv - CC0;
      const unsigned short* hr = hb + (size_t)row * (PD0 + PD1) + lane * 4;
      const unsigned short* w0r = w0b + (size_t)rel * PD0 + lane * 4;
      uint2 ha = *(const uint2*)hr, wa0 = *(const uint2*)w0r;
      cl = bfl(ha.x) * bfl(wa0.x) + bfh(ha.x) * bfh(wa0.x)
         + bfl(ha.y) * bfl(wa0.y) + bfh(ha.y) * bfh(wa0.y);
    } else {
      int rel = yv - CC1;
      cl = bf1(hb[(size_t)row * (PD0 + PD1) + PD0 + lane])
         * bf1(w1b[(size_t)rel * PD1 + lane]);
    }
#pragma unroll
    for (int d = 1; d < 64; d <<= 1) cl += __shfl_xor(cl, d);
  }
  if (lane == 0) { ht[row] = s + head_b[th]; tc[row] = (yv < CC0) ? 0.f : cl; }
}

__global__ void finalize_kernel(const float* __restrict__ hs, const float* __restrict__ ht,
                                const float* __restrict__ s0, const float* __restrict__ s1,
                                const float* __restrict__ tc,
                                const int* __restrict__ y, float* __restrict__ out) {
  __shared__ float red[256];
  float local = 0.f;
  for (int n = threadIdx.x; n < NROWS; n += 256) {
    int yv = y[n];
    float o = ht[n] - logf(hs[n]);
    if (yv >= CC0) o += tc[n] - logf(yv < CC1 ? s0[n] : s1[n]);
    out[n] = o;
    local += o;
  }
  red[threadIdx.x] = local;
  __syncthreads();
  for (int s = 128; s > 0; s >>= 1) {
    if ((int)threadIdx.x < s) red[threadIdx.x] += red[threadIdx.x + s];
    __syncthreads();
  }
  if (threadIdx.x == 0) out[NROWS] = -red[0] / (float)NROWS;
}

extern "C" void kernel_launch(void* const* d_in, const int* in_sizes, int n_in,
                              void* d_out, int out_size, void* d_ws, size_t ws_size,
                              hipStream_t stream) {
  const float* x      = (const float*)d_in[0];
  const int*   y      = (const int*)d_in[1];
  const float* head_w = (const float*)d_in[2];
  const float* head_b = (const float*)d_in[3];
  const float* proj0  = (const float*)d_in[4];
  const float* w0     = (const float*)d_in[5];
  const float* proj1  = (const float*)d_in[6];
  const float* w1     = (const float*)d_in[7];
  float* out = (float*)d_out;

  char* wp = (char*)d_ws;
  unsigned short* xb  = (unsigned short*)wp; wp += (size_t)NROWS * NHID * 2;
  unsigned short* hpb = (unsigned short*)wp; wp += (size_t)HPN * NHID * 2;
  unsigned short* w0b = (unsigned short*)wp; wp += (size_t)TSZ0 * PD0 * 2;
  unsigned short* w1b = (unsigned short*)wp; wp += (size_t)TSZ1 * PD1 * 2;
  unsigned short* hb  = (unsigned short*)wp; wp += (size_t)NROWS * (PD0 + PD1) * 2;
  float* hs = (float*)wp; wp += NROWS * 4;
  float* s0 = (float*)wp; wp += NROWS * 4;
  float* s1 = (float*)wp; wp += NROWS * 4;
  float* ht = (float*)wp; wp += NROWS * 4;
  float* tc = (float*)wp; wp += NROWS * 4;

  hipMemsetAsync(hs, 0, 3 * NROWS * 4, stream);   // zero hs, s0, s1

  auto conv = [&](const float* s, unsigned short* d, int n) {
    int n4 = n / 4;
    int blocks = (n4 + 255) / 256; if (blocks > 2048) blocks = 2048;
    convert_f32_bf16<<<dim3(blocks), dim3(256), 0, stream>>>(s, d, n4);
  };
  conv(x,      xb,  NROWS * NHID);
  conv(head_w, hpb, HEADSZ * NHID);
  conv(proj0,  hpb + (size_t)HEADSZ * NHID, PD0 * NHID);
  conv(proj1,  hpb + (size_t)(HEADSZ + PD0) * NHID, PD1 * NHID);
  conv(w0,     w0b, TSZ0 * PD0);
  conv(w1,     w1b, TSZ1 * PD1);

  // head + proj fused: cols [0,1677) -> exp-sum; cols [1677,1997) -> hb store
  gemm_fused<<<dim3(512), 256, 0, stream>>>(
      xb, NHID, hpb, NHID, HPN, NHID, 1,
      head_b, hs, hb, PD0 + PD1, HEADSZ);
  // target logits (needs hb) — one wave per row
  target_logits<<<dim3(NROWS / 4), 256, 0, stream>>>(
      xb, hpb, head_b, hb, w0b, w1b, y, ht, tc);
  // cluster 0: nTiles=27, tpc=3 -> 9 chunks x 32 = 288 blocks
  gemm_fused<<<dim3(288), 256, 0, stream>>>(
      hb, PD0 + PD1, w0b, PD0, TSZ0, PD0, 3,
      nullptr, s0, nullptr, 0, 0);
  // cluster 1: register-direct, no LDS: 59 chunks x 32 rowBlks = 1888 blocks
  gemm_c1_reg<<<dim3(1888), 256, 0, stream>>>(hb + PD0, w1b, s1);

  finalize_kernel<<<1, 256, 0, stream>>>(hs, ht, s0, s1, tc, y, out);
}